// Round 2
// baseline (270.979 us; speedup 1.0000x reference)
//
#include <hip/hip_runtime.h>
#include <hip/hip_bf16.h>

#define HDIM 128

typedef short bf16x8 __attribute__((ext_vector_type(8)));
typedef float f32x4 __attribute__((ext_vector_type(4)));

// fp32 -> bf16 (RNE; compiler can fuse pairs into v_cvt_pk_bf16_f32)
__device__ __forceinline__ short f2bf(float f) {
    __hip_bfloat16 h = __float2bfloat16(f);
    return __builtin_bit_cast(short, h);
}

__device__ __forceinline__ float bf2f(short s) {
    unsigned u = ((unsigned)(unsigned short)s) << 16;
    return __builtin_bit_cast(float, u);
}

// B-fragment read from swizzled WT[n][k] LDS image (16B, contiguous 8 k at column n)
__device__ __forceinline__ bf16x8 ldB(const short* sW, int n, int chunk) {
    return *(const bf16x8*)(sW + n * HDIM + ((chunk ^ (n & 7)) << 3));
}

// A-fragment from fp32 x: 8 consecutive k of x[src]*x[dst]
__device__ __forceinline__ bf16x8 gatherA_f32(const float* xs, const float* xd, int k0) {
    float4 a0 = *(const float4*)(xs + k0);
    float4 a1 = *(const float4*)(xs + k0 + 4);
    float4 c0 = *(const float4*)(xd + k0);
    float4 c1 = *(const float4*)(xd + k0 + 4);
    bf16x8 r = { f2bf(a0.x * c0.x), f2bf(a0.y * c0.y), f2bf(a0.z * c0.z), f2bf(a0.w * c0.w),
                 f2bf(a1.x * c1.x), f2bf(a1.y * c1.y), f2bf(a1.z * c1.z), f2bf(a1.w * c1.w) };
    return r;
}

// A-fragment from pre-converted bf16 x: half the gather bytes
__device__ __forceinline__ bf16x8 gatherA_bf16(const unsigned short* xs, const unsigned short* xd, int k0) {
    bf16x8 va = *(const bf16x8*)(xs + k0);
    bf16x8 vb = *(const bf16x8*)(xd + k0);
    bf16x8 r;
    #pragma unroll
    for (int j = 0; j < 8; ++j) r[j] = f2bf(bf2f(va[j]) * bf2f(vb[j]));
    return r;
}

__global__ void cvt_kernel(const float* __restrict__ x, unsigned short* __restrict__ xb, int n4) {
    int i = blockIdx.x * blockDim.x + threadIdx.x;
    const int stride = gridDim.x * blockDim.x;
    for (; i < n4; i += stride) {
        float4 v = ((const float4*)x)[i];
        ushort4 o;
        o.x = (unsigned short)f2bf(v.x);
        o.y = (unsigned short)f2bf(v.y);
        o.z = (unsigned short)f2bf(v.z);
        o.w = (unsigned short)f2bf(v.w);
        ((ushort4*)xb)[i] = o;
    }
}

template<bool XBF>
__global__ __launch_bounds__(1024, 4)
void edge_mlp_kernel(const float* __restrict__ x,
                     const unsigned short* __restrict__ xb,
                     const int* __restrict__ src,
                     const int* __restrict__ dst,
                     const float* __restrict__ W1, const float* __restrict__ b1,
                     const float* __restrict__ W2, const float* __restrict__ b2,
                     const float* __restrict__ W3, const float* __restrict__ b3,
                     float* __restrict__ out, int E, int ntiles)
{
    // 128 KB total -> 1 block/CU x 16 waves = 16 waves/CU (VGPR=128 cap)
    __shared__ short sW1[HDIM * HDIM];       // WT1[n][k] bf16, chunk-swizzled (32 KB)
    __shared__ short sW2[HDIM * HDIM];       // WT2[n][k] bf16, chunk-swizzled (32 KB)
    __shared__ short sH1[16][32 * 64];       // per-wave H1 transpose staging, one k-half (64 KB)

    const int tid = threadIdx.x;

    // ---- stage weights: global fp32 [k][n] -> LDS bf16 WT[n][k], swizzled ----
    {
        const int n  = tid & 127;
        const int kh = tid >> 7;             // 0..7
        #pragma unroll
        for (int c = 0; c < 2; ++c) {
            const int kc = kh * 2 + c;       // 16B chunk index, 0..15
            const int k0 = kc * 8;
            short v1[8], v2[8];
            #pragma unroll
            for (int j = 0; j < 8; ++j) {
                v1[j] = f2bf(W1[(k0 + j) * HDIM + n]);
                v2[j] = f2bf(W2[(k0 + j) * HDIM + n]);
            }
            const int off = n * HDIM + ((kc ^ (n & 7)) << 3);
            bf16x8 t1 = { v1[0], v1[1], v1[2], v1[3], v1[4], v1[5], v1[6], v1[7] };
            bf16x8 t2 = { v2[0], v2[1], v2[2], v2[3], v2[4], v2[5], v2[6], v2[7] };
            *(bf16x8*)(sW1 + off) = t1;
            *(bf16x8*)(sW2 + off) = t2;
        }
    }
    __syncthreads();   // only barrier; weights are read-only afterwards

    const int w    = tid >> 6;      // wave 0..15
    const int lane = tid & 63;
    const int g    = lane >> 4;     // 16-lane group 0..3
    const int e16  = lane & 15;
    short* myH1 = &sH1[w][0];

    // per-lane hoisted bias / W3 values (column = 16*nt + e16)
    float b1v[8], b2v[8], w3v[8];
    #pragma unroll
    for (int nt = 0; nt < 8; ++nt) {
        b1v[nt] = b1[nt * 16 + e16];
        b2v[nt] = b2[nt * 16 + e16];
        w3v[nt] = W3[nt * 16 + e16];
    }
    const float b3s = b3[0];

    // ---- persistent loop with next-tile index prefetch ----
    int tile = blockIdx.x;
    int s0 = 0, d0 = 0, s1 = 0, d1 = 0;
    if (tile < ntiles) {
        const int base = (tile << 9) + (w << 5);
        int a0 = base + e16;       a0 = a0 < E ? a0 : 0;
        int a1 = base + 16 + e16;  a1 = a1 < E ? a1 : 0;
        s0 = src[a0]; d0 = dst[a0]; s1 = src[a1]; d1 = dst[a1];
    }

    for (; tile < ntiles; ) {
        const int nxt = tile + gridDim.x;
        int ps0 = 0, pd0 = 0, ps1 = 0, pd1 = 0;
        if (nxt < ntiles) {
            const int nb = (nxt << 9) + (w << 5);
            int a0 = nb + e16;       a0 = a0 < E ? a0 : 0;
            int a1 = nb + 16 + e16;  a1 = a1 < E ? a1 : 0;
            ps0 = src[a0]; pd0 = dst[a0]; ps1 = src[a1]; pd1 = dst[a1];
        }

        const int base = (tile << 9) + (w << 5);   // this wave's 32 edges

        // ---------- GEMM1: H1 = relu(G @ W1 + b1), G built in-register ----------
        f32x4 acc[2][8];
        #pragma unroll
        for (int nt = 0; nt < 8; ++nt) {
            f32x4 iv = { b1v[nt], b1v[nt], b1v[nt], b1v[nt] };
            acc[0][nt] = iv;
            acc[1][nt] = iv;
        }

        if constexpr (XBF) {
            const unsigned short* xs0 = xb + (size_t)s0 * HDIM;
            const unsigned short* xd0 = xb + (size_t)d0 * HDIM;
            const unsigned short* xs1 = xb + (size_t)s1 * HDIM;
            const unsigned short* xd1 = xb + (size_t)d1 * HDIM;
            #pragma unroll
            for (int t = 0; t < 4; ++t) {
                const int k0 = t * 32 + g * 8;
                bf16x8 a0 = gatherA_bf16(xs0, xd0, k0);
                bf16x8 a1 = gatherA_bf16(xs1, xd1, k0);
                #pragma unroll
                for (int nt = 0; nt < 8; ++nt) {
                    bf16x8 bb = ldB(sW1, nt * 16 + e16, t * 4 + g);
                    acc[0][nt] = __builtin_amdgcn_mfma_f32_16x16x32_bf16(a0, bb, acc[0][nt], 0, 0, 0);
                    acc[1][nt] = __builtin_amdgcn_mfma_f32_16x16x32_bf16(a1, bb, acc[1][nt], 0, 0, 0);
                }
            }
        } else {
            const float* xs0 = x + (size_t)s0 * HDIM;
            const float* xd0 = x + (size_t)d0 * HDIM;
            const float* xs1 = x + (size_t)s1 * HDIM;
            const float* xd1 = x + (size_t)d1 * HDIM;
            #pragma unroll
            for (int t = 0; t < 4; ++t) {
                const int k0 = t * 32 + g * 8;
                bf16x8 a0 = gatherA_f32(xs0, xd0, k0);
                bf16x8 a1 = gatherA_f32(xs1, xd1, k0);
                #pragma unroll
                for (int nt = 0; nt < 8; ++nt) {
                    bf16x8 bb = ldB(sW1, nt * 16 + e16, t * 4 + g);
                    acc[0][nt] = __builtin_amdgcn_mfma_f32_16x16x32_bf16(a0, bb, acc[0][nt], 0, 0, 0);
                    acc[1][nt] = __builtin_amdgcn_mfma_f32_16x16x32_bf16(a1, bb, acc[1][nt], 0, 0, 0);
                }
            }
        }

        // ---------- GEMM2: H2 = relu(H1 @ W2 + b2), H1 staged per-wave in 2 k-halves ----------
        f32x4 acc2[2][8];
        #pragma unroll
        for (int nt = 0; nt < 8; ++nt) {
            f32x4 iv = { b2v[nt], b2v[nt], b2v[nt], b2v[nt] };
            acc2[0][nt] = iv;
            acc2[1][nt] = iv;
        }
        #pragma unroll
        for (int khf = 0; khf < 2; ++khf) {
            // write relu(H1) columns 64*khf .. +63 transposed into myH1[e][kk] (swizzled)
            #pragma unroll
            for (int ntl = 0; ntl < 4; ++ntl) {
                const int nt = khf * 4 + ntl;
                #pragma unroll
                for (int mt = 0; mt < 2; ++mt) {
                    #pragma unroll
                    for (int r = 0; r < 4; ++r) {
                        const int e  = mt * 16 + g * 4 + r;   // edge-row within wave tile
                        const int kk = ntl * 16 + e16;        // k within this half
                        float v = acc[mt][nt][r];
                        v = v > 0.0f ? v : 0.0f;
                        myH1[e * 64 + (((kk >> 3) ^ (e & 7)) << 3) + (kk & 7)] = f2bf(v);
                    }
                }
            }
            // consume this half: k-steps t2 = 2*khf + {0,1}
            #pragma unroll
            for (int tl = 0; tl < 2; ++tl) {
                const int ck = tl * 4 + g;                    // chunk within half
                bf16x8 a0 = *(const bf16x8*)(myH1 + e16 * 64 + ((ck ^ (e16 & 7)) << 3));
                bf16x8 a1 = *(const bf16x8*)(myH1 + (e16 + 16) * 64 + ((ck ^ ((e16 + 16) & 7)) << 3));
                const int t2 = khf * 2 + tl;
                #pragma unroll
                for (int nt = 0; nt < 8; ++nt) {
                    bf16x8 bb = ldB(sW2, nt * 16 + e16, t2 * 4 + g);
                    acc2[0][nt] = __builtin_amdgcn_mfma_f32_16x16x32_bf16(a0, bb, acc2[0][nt], 0, 0, 0);
                    acc2[1][nt] = __builtin_amdgcn_mfma_f32_16x16x32_bf16(a1, bb, acc2[1][nt], 0, 0, 0);
                }
            }
        }

        // ---------- final: out = relu(H2) @ W3 + b3 (fp32), 16-lane butterfly ----------
        #pragma unroll
        for (int mt = 0; mt < 2; ++mt) {
            float p0 = 0.f, p1 = 0.f, p2 = 0.f, p3 = 0.f;
            #pragma unroll
            for (int nt = 0; nt < 8; ++nt) {
                f32x4 v = acc2[mt][nt];
                float r0 = v[0] > 0.f ? v[0] : 0.f;
                float r1 = v[1] > 0.f ? v[1] : 0.f;
                float r2 = v[2] > 0.f ? v[2] : 0.f;
                float r3 = v[3] > 0.f ? v[3] : 0.f;
                p0 += r0 * w3v[nt];
                p1 += r1 * w3v[nt];
                p2 += r2 * w3v[nt];
                p3 += r3 * w3v[nt];
            }
            #pragma unroll
            for (int off = 1; off < 16; off <<= 1) {
                p0 += __shfl_xor(p0, off);
                p1 += __shfl_xor(p1, off);
                p2 += __shfl_xor(p2, off);
                p3 += __shfl_xor(p3, off);
            }
            if (e16 == 0) {
                const int eb = base + mt * 16 + g * 4;   // rows 4g..4g+3 of this sub-tile
                if (eb + 0 < E) out[eb + 0] = p0 + b3s;
                if (eb + 1 < E) out[eb + 1] = p1 + b3s;
                if (eb + 2 < E) out[eb + 2] = p2 + b3s;
                if (eb + 3 < E) out[eb + 3] = p3 + b3s;
            }
        }

        tile = nxt;
        s0 = ps0; d0 = pd0; s1 = ps1; d1 = pd1;
    }
}

extern "C" void kernel_launch(void* const* d_in, const int* in_sizes, int n_in,
                              void* d_out, int out_size, void* d_ws, size_t ws_size,
                              hipStream_t stream) {
    const float* x   = (const float*)d_in[0];
    const int*   src = (const int*)d_in[1];
    const int*   dst = (const int*)d_in[2];
    const float* W1  = (const float*)d_in[3];
    const float* b1  = (const float*)d_in[4];
    const float* W2  = (const float*)d_in[5];
    const float* b2  = (const float*)d_in[6];
    const float* W3  = (const float*)d_in[7];
    const float* b3  = (const float*)d_in[8];
    float* out = (float*)d_out;

    const int xelems = in_sizes[0];           // N_NODES * 128
    const int E = in_sizes[1];
    const int ntiles = (E + 511) >> 9;        // 512 edges per block-tile
    const int grid = ntiles < 256 ? ntiles : 256;   // persistent: 1 block/CU

    const size_t need = (size_t)xelems * sizeof(unsigned short);
    if (ws_size >= need) {
        unsigned short* xb = (unsigned short*)d_ws;
        const int n4 = xelems >> 2;
        hipLaunchKernelGGL(cvt_kernel, dim3(2048), dim3(256), 0, stream, x, xb, n4);
        hipLaunchKernelGGL((edge_mlp_kernel<true>), dim3(grid), dim3(1024), 0, stream,
                           x, xb, src, dst, W1, b1, W2, b2, W3, b3, out, E, ntiles);
    } else {
        hipLaunchKernelGGL((edge_mlp_kernel<false>), dim3(grid), dim3(1024), 0, stream,
                           x, (const unsigned short*)nullptr, src, dst,
                           W1, b1, W2, b2, W3, b3, out, E, ntiles);
    }
}

// Round 3
// 91.429 us; speedup vs baseline: 2.9638x; 2.9638x over previous
//
#include <hip/hip_runtime.h>
#include <hip/hip_bf16.h>

#define HDIM 128

typedef short bf16x8 __attribute__((ext_vector_type(8)));
typedef float f32x4 __attribute__((ext_vector_type(4)));

// fp32 -> bf16 RNE
__device__ __forceinline__ short f2bf(float f) {
    __hip_bfloat16 h = __float2bfloat16(f);
    return __builtin_bit_cast(short, h);
}

__device__ __forceinline__ float bf2f(short s) {
    unsigned u = ((unsigned)(unsigned short)s) << 16;
    return __builtin_bit_cast(float, u);
}

// B-fragment read from swizzled WT[n][k] LDS image (16B, contiguous 8 k at column n)
__device__ __forceinline__ bf16x8 ldB(const short* sW, int n, int chunk) {
    return *(const bf16x8*)(sW + n * HDIM + ((chunk ^ (n & 7)) << 3));
}

// A-fragment from fp32 x (fallback path)
__device__ __forceinline__ bf16x8 gatherA_f32(const float* xs, const float* xd, int k0) {
    float4 a0 = *(const float4*)(xs + k0);
    float4 a1 = *(const float4*)(xs + k0 + 4);
    float4 c0 = *(const float4*)(xd + k0);
    float4 c1 = *(const float4*)(xd + k0 + 4);
    bf16x8 r = { f2bf(a0.x * c0.x), f2bf(a0.y * c0.y), f2bf(a0.z * c0.z), f2bf(a0.w * c0.w),
                 f2bf(a1.x * c1.x), f2bf(a1.y * c1.y), f2bf(a1.z * c1.z), f2bf(a1.w * c1.w) };
    return r;
}

__global__ void cvt_kernel(const float* __restrict__ x, unsigned short* __restrict__ xb, int n4) {
    int i = blockIdx.x * blockDim.x + threadIdx.x;
    const int stride = gridDim.x * blockDim.x;
    for (; i < n4; i += stride) {
        float4 v = ((const float4*)x)[i];
        ushort4 o;
        o.x = (unsigned short)f2bf(v.x);
        o.y = (unsigned short)f2bf(v.y);
        o.z = (unsigned short)f2bf(v.z);
        o.w = (unsigned short)f2bf(v.w);
        ((ushort4*)xb)[i] = o;
    }
}

template<bool XBF>
__global__ __launch_bounds__(256, 2)
void edge_mlp_kernel(const float* __restrict__ x,
                     const unsigned short* __restrict__ xb,
                     const int* __restrict__ src,
                     const int* __restrict__ dst,
                     const float* __restrict__ W1, const float* __restrict__ b1,
                     const float* __restrict__ W2, const float* __restrict__ b2,
                     const float* __restrict__ W3, const float* __restrict__ b3,
                     float* __restrict__ out, int E, int ntiles)
{
    // 80 KB -> LDS-bound at 2 blocks/CU (8 waves/CU); VGPR budget up to 256 is free
    __shared__ short sW1[HDIM * HDIM];      // WT1[n][k] bf16, chunk-swizzled (32 KB)
    __shared__ short sW2[HDIM * HDIM];      // WT2[n][k] bf16, chunk-swizzled (32 KB)
    __shared__ short sH1[4][32 * 64];       // per-wave H1 transpose staging (16 KB)

    const int tid = threadIdx.x;

    // ---- stage weights: global fp32 [k][n] -> LDS bf16 WT[n][k], swizzled ----
    {
        const int n  = tid & 127;
        const int kh = tid >> 7;            // 0 or 1
        for (int c = 0; c < 8; ++c) {
            const int kc = kh * 8 + c;      // 16B chunk index, 0..15
            const int k0 = kc * 8;
            short v1[8], v2[8];
            #pragma unroll
            for (int j = 0; j < 8; ++j) {
                v1[j] = f2bf(W1[(k0 + j) * HDIM + n]);
                v2[j] = f2bf(W2[(k0 + j) * HDIM + n]);
            }
            const int off = n * HDIM + ((kc ^ (n & 7)) << 3);
            bf16x8 t1 = { v1[0], v1[1], v1[2], v1[3], v1[4], v1[5], v1[6], v1[7] };
            bf16x8 t2 = { v2[0], v2[1], v2[2], v2[3], v2[4], v2[5], v2[6], v2[7] };
            *(bf16x8*)(sW1 + off) = t1;
            *(bf16x8*)(sW2 + off) = t2;
        }
    }
    __syncthreads();   // only barrier; weights read-only afterwards

    const int w    = tid >> 6;      // wave 0..3
    const int lane = tid & 63;
    const int g    = lane >> 4;     // 16-lane group 0..3
    const int e16  = lane & 15;
    short* myH1 = &sH1[w][0];

    float b1v[8], b2v[8], w3v[8];
    #pragma unroll
    for (int nt = 0; nt < 8; ++nt) {
        b1v[nt] = b1[nt * 16 + e16];
        b2v[nt] = b2[nt * 16 + e16];
        w3v[nt] = W3[nt * 16 + e16];
    }
    const float b3s = b3[0];

    if (blockIdx.x >= ntiles) return;

    // ---- pipeline state: indices + raw bf16 x-slices for the CURRENT tile ----
    int tile = blockIdx.x;
    int s0, d0, s1, d1;
    {
        const int base = (tile << 7) + (w << 5);
        int a0 = base + e16;       a0 = a0 < E ? a0 : 0;
        int a1 = base + 16 + e16;  a1 = a1 < E ? a1 : 0;
        s0 = src[a0]; d0 = dst[a0]; s1 = src[a1]; d1 = dst[a1];
    }
    bf16x8 rS0[4], rD0[4], rS1[4], rD1[4];   // 64 VGPRs raw A-data
    if constexpr (XBF) {
        const unsigned short* pxs0 = xb + (size_t)s0 * HDIM;
        const unsigned short* pxd0 = xb + (size_t)d0 * HDIM;
        const unsigned short* pxs1 = xb + (size_t)s1 * HDIM;
        const unsigned short* pxd1 = xb + (size_t)d1 * HDIM;
        #pragma unroll
        for (int t = 0; t < 4; ++t) {
            const int k0 = t * 32 + g * 8;
            rS0[t] = *(const bf16x8*)(pxs0 + k0);
            rD0[t] = *(const bf16x8*)(pxd0 + k0);
            rS1[t] = *(const bf16x8*)(pxs1 + k0);
            rD1[t] = *(const bf16x8*)(pxd1 + k0);
        }
    }

    for (;;) {
        const int nxt = tile + gridDim.x;
        const bool hasNext = nxt < ntiles;

        // prefetch next tile's indices (resolves during GEMM1)
        int ns0, nd0, ns1, nd1;
        {
            const int nb = hasNext ? (nxt << 7) + (w << 5) : 0;
            int a0 = nb + e16;       a0 = a0 < E ? a0 : 0;
            int a1 = nb + 16 + e16;  a1 = a1 < E ? a1 : 0;
            ns0 = src[a0]; nd0 = dst[a0]; ns1 = src[a1]; nd1 = dst[a1];
        }

        const int base = (tile << 7) + (w << 5);

        // ---------- GEMM1: H1 = relu(G @ W1 + b1) ----------
        f32x4 acc[2][8];
        #pragma unroll
        for (int nt = 0; nt < 8; ++nt) {
            f32x4 iv = { b1v[nt], b1v[nt], b1v[nt], b1v[nt] };
            acc[0][nt] = iv;
            acc[1][nt] = iv;
        }

        if constexpr (XBF) {
            #pragma unroll
            for (int t = 0; t < 4; ++t) {
                bf16x8 a0, a1;
                #pragma unroll
                for (int j = 0; j < 8; ++j) {
                    a0[j] = f2bf(bf2f(rS0[t][j]) * bf2f(rD0[t][j]));
                    a1[j] = f2bf(bf2f(rS1[t][j]) * bf2f(rD1[t][j]));
                }
                #pragma unroll
                for (int nt = 0; nt < 8; ++nt) {
                    bf16x8 bb = ldB(sW1, nt * 16 + e16, t * 4 + g);
                    acc[0][nt] = __builtin_amdgcn_mfma_f32_16x16x32_bf16(a0, bb, acc[0][nt], 0, 0, 0);
                    acc[1][nt] = __builtin_amdgcn_mfma_f32_16x16x32_bf16(a1, bb, acc[1][nt], 0, 0, 0);
                }
            }
        } else {
            const float* xs0 = x + (size_t)s0 * HDIM;
            const float* xd0 = x + (size_t)d0 * HDIM;
            const float* xs1 = x + (size_t)s1 * HDIM;
            const float* xd1 = x + (size_t)d1 * HDIM;
            #pragma unroll
            for (int t = 0; t < 4; ++t) {
                const int k0 = t * 32 + g * 8;
                bf16x8 a0 = gatherA_f32(xs0, xd0, k0);
                bf16x8 a1 = gatherA_f32(xs1, xd1, k0);
                #pragma unroll
                for (int nt = 0; nt < 8; ++nt) {
                    bf16x8 bb = ldB(sW1, nt * 16 + e16, t * 4 + g);
                    acc[0][nt] = __builtin_amdgcn_mfma_f32_16x16x32_bf16(a0, bb, acc[0][nt], 0, 0, 0);
                    acc[1][nt] = __builtin_amdgcn_mfma_f32_16x16x32_bf16(a1, bb, acc[1][nt], 0, 0, 0);
                }
            }
        }

        // ---------- issue next tile's raw gathers; latency hides under GEMM2 ----------
        bf16x8 nS0[4], nD0[4], nS1[4], nD1[4];
        if constexpr (XBF) {
            const unsigned short* pxs0 = xb + (size_t)ns0 * HDIM;
            const unsigned short* pxd0 = xb + (size_t)nd0 * HDIM;
            const unsigned short* pxs1 = xb + (size_t)ns1 * HDIM;
            const unsigned short* pxd1 = xb + (size_t)nd1 * HDIM;
            #pragma unroll
            for (int t = 0; t < 4; ++t) {
                const int k0 = t * 32 + g * 8;
                nS0[t] = *(const bf16x8*)(pxs0 + k0);
                nD0[t] = *(const bf16x8*)(pxd0 + k0);
                nS1[t] = *(const bf16x8*)(pxs1 + k0);
                nD1[t] = *(const bf16x8*)(pxd1 + k0);
            }
        }

        // ---------- GEMM2: H2 = relu(H1 @ W2 + b2) ----------
        f32x4 acc2[2][8];
        #pragma unroll
        for (int nt = 0; nt < 8; ++nt) {
            f32x4 iv = { b2v[nt], b2v[nt], b2v[nt], b2v[nt] };
            acc2[0][nt] = iv;
            acc2[1][nt] = iv;
        }
        #pragma unroll
        for (int khf = 0; khf < 2; ++khf) {
            #pragma unroll
            for (int ntl = 0; ntl < 4; ++ntl) {
                const int nt = khf * 4 + ntl;
                #pragma unroll
                for (int mt = 0; mt < 2; ++mt) {
                    #pragma unroll
                    for (int r = 0; r < 4; ++r) {
                        const int e  = mt * 16 + g * 4 + r;
                        const int kk = ntl * 16 + e16;
                        float v = acc[mt][nt][r];
                        v = v > 0.0f ? v : 0.0f;
                        myH1[e * 64 + (((kk >> 3) ^ (e & 7)) << 3) + (kk & 7)] = f2bf(v);
                    }
                }
            }
            #pragma unroll
            for (int tl = 0; tl < 2; ++tl) {
                const int ck = tl * 4 + g;
                bf16x8 a0 = *(const bf16x8*)(myH1 + e16 * 64 + ((ck ^ (e16 & 7)) << 3));
                bf16x8 a1 = *(const bf16x8*)(myH1 + (e16 + 16) * 64 + ((ck ^ ((e16 + 16) & 7)) << 3));
                const int t2 = khf * 2 + tl;
                #pragma unroll
                for (int nt = 0; nt < 8; ++nt) {
                    bf16x8 bb = ldB(sW2, nt * 16 + e16, t2 * 4 + g);
                    acc2[0][nt] = __builtin_amdgcn_mfma_f32_16x16x32_bf16(a0, bb, acc2[0][nt], 0, 0, 0);
                    acc2[1][nt] = __builtin_amdgcn_mfma_f32_16x16x32_bf16(a1, bb, acc2[1][nt], 0, 0, 0);
                }
            }
        }

        // ---------- final: out = relu(H2) @ W3 + b3 ----------
        #pragma unroll
        for (int mt = 0; mt < 2; ++mt) {
            float p0 = 0.f, p1 = 0.f, p2 = 0.f, p3 = 0.f;
            #pragma unroll
            for (int nt = 0; nt < 8; ++nt) {
                f32x4 v = acc2[mt][nt];
                float r0 = v[0] > 0.f ? v[0] : 0.f;
                float r1 = v[1] > 0.f ? v[1] : 0.f;
                float r2 = v[2] > 0.f ? v[2] : 0.f;
                float r3 = v[3] > 0.f ? v[3] : 0.f;
                p0 += r0 * w3v[nt];
                p1 += r1 * w3v[nt];
                p2 += r2 * w3v[nt];
                p3 += r3 * w3v[nt];
            }
            #pragma unroll
            for (int off = 1; off < 16; off <<= 1) {
                p0 += __shfl_xor(p0, off);
                p1 += __shfl_xor(p1, off);
                p2 += __shfl_xor(p2, off);
                p3 += __shfl_xor(p3, off);
            }
            if (e16 == 0) {
                const int eb = base + mt * 16 + g * 4;
                if (eb + 0 < E) out[eb + 0] = p0 + b3s;
                if (eb + 1 < E) out[eb + 1] = p1 + b3s;
                if (eb + 2 < E) out[eb + 2] = p2 + b3s;
                if (eb + 3 < E) out[eb + 3] = p3 + b3s;
            }
        }

        if (!hasNext) break;
        tile = nxt;
        s0 = ns0; d0 = nd0; s1 = ns1; d1 = nd1;
        if constexpr (XBF) {
            #pragma unroll
            for (int t = 0; t < 4; ++t) {
                rS0[t] = nS0[t]; rD0[t] = nD0[t];
                rS1[t] = nS1[t]; rD1[t] = nD1[t];
            }
        }
    }
}

extern "C" void kernel_launch(void* const* d_in, const int* in_sizes, int n_in,
                              void* d_out, int out_size, void* d_ws, size_t ws_size,
                              hipStream_t stream) {
    const float* x   = (const float*)d_in[0];
    const int*   src = (const int*)d_in[1];
    const int*   dst = (const int*)d_in[2];
    const float* W1  = (const float*)d_in[3];
    const float* b1  = (const float*)d_in[4];
    const float* W2  = (const float*)d_in[5];
    const float* b2  = (const float*)d_in[6];
    const float* W3  = (const float*)d_in[7];
    const float* b3  = (const float*)d_in[8];
    float* out = (float*)d_out;

    const int xelems = in_sizes[0];           // N_NODES * 128
    const int E = in_sizes[1];
    const int ntiles = (E + 127) >> 7;        // 128 edges per block-tile
    const int grid = ntiles < 512 ? ntiles : 512;   // persistent: 2 blocks/CU

    const size_t need = (size_t)xelems * sizeof(unsigned short);
    if (ws_size >= need) {
        unsigned short* xb = (unsigned short*)d_ws;
        const int n4 = xelems >> 2;
        hipLaunchKernelGGL(cvt_kernel, dim3(2048), dim3(256), 0, stream, x, xb, n4);
        hipLaunchKernelGGL((edge_mlp_kernel<true>), dim3(grid), dim3(256), 0, stream,
                           x, xb, src, dst, W1, b1, W2, b2, W3, b3, out, E, ntiles);
    } else {
        hipLaunchKernelGGL((edge_mlp_kernel<false>), dim3(grid), dim3(256), 0, stream,
                           x, (const unsigned short*)nullptr, src, dst,
                           W1, b1, W2, b2, W3, b3, out, E, ntiles);
    }
}